// Round 10
// baseline (700.854 us; speedup 1.0000x reference)
//
#include <hip/hip_runtime.h>

#define N_NODES  50000
#define N_EDGES  800000
#define DIM      128
#define N_GRAPHS 256
#define N_CLASSES 16
#define N_LAYERS 5
#define BN_EPS   1e-5f

#define GEMM_BM 64
#define LDSP 136   // padded LDS row stride (bf16 elems): 272B breaks power-of-2 banking

typedef short bf16x8 __attribute__((ext_vector_type(8)));
typedef float f32x4  __attribute__((ext_vector_type(4)));

__device__ __forceinline__ float bf2f(unsigned short u) {
    unsigned int x = ((unsigned int)u) << 16;
    return __builtin_bit_cast(float, x);
}
__device__ __forceinline__ unsigned short f2bf(float f) {
    unsigned int x = __builtin_bit_cast(unsigned int, f);
    x += 0x7fffu + ((x >> 16) & 1u);   // RNE
    return (unsigned short)(x >> 16);
}
__device__ __forceinline__ float lo16(unsigned int v) { return bf2f((unsigned short)(v & 0xffffu)); }
__device__ __forceinline__ float hi16(unsigned int v) { return bf2f((unsigned short)(v >> 16)); }
__device__ __forceinline__ unsigned int pack16(float a, float b) {
    return (unsigned int)f2bf(a) | ((unsigned int)f2bf(b) << 16);
}

// ---------------- CSR build: deg histogram + graph boundaries (merged) ----------------

__global__ void degbound_kernel(const int* __restrict__ dst, int* __restrict__ deg,
                                const int* __restrict__ gid, int* __restrict__ gptr) {
    int i = blockIdx.x * blockDim.x + threadIdx.x;
    if (i < N_EDGES) atomicAdd(&deg[dst[i]], 1);
    if (i < N_NODES) {
        int cur = gid[i];
        int prev = (i == 0) ? -1 : gid[i - 1];
        for (int g = prev + 1; g <= cur; ++g) gptr[g] = i;
        if (i == N_NODES - 1)
            for (int g = cur + 1; g <= N_GRAPHS; ++g) gptr[g] = N_NODES;
    }
}

__global__ void fill_csr_kernel(const int* __restrict__ src, const int* __restrict__ dst,
                                int* __restrict__ cursor, int* __restrict__ csr, int e_count) {
    int e = blockIdx.x * blockDim.x + threadIdx.x;
    if (e < e_count) {
        int d = dst[e];
        int p = atomicAdd(&cursor[d], 1);
        csr[p] = src[e];
    }
}

// zero the gather-fallback row (index N_NODES) of the two h ping-pong buffers
__global__ void zrow_kernel(unsigned short* __restrict__ a, unsigned short* __restrict__ b) {
    int t = threadIdx.x;   // 64 threads
    uint2 z = make_uint2(0u, 0u);
    if (t < 32) ((uint2*)(a + (size_t)N_NODES * DIM))[t] = z;
    else        ((uint2*)(b + (size_t)N_NODES * DIM))[t - 32] = z;
}

// ---------------- fast 3-phase exclusive scan (rowptr over 50000 degrees) ----------------

__global__ __launch_bounds__(1024) void scan_part_kernel(const int* __restrict__ in,
                                                         int* __restrict__ part, int n) {
    __shared__ int red[16];
    int tid = threadIdx.x;
    int i = blockIdx.x * 1024 + tid;
    int v = (i < n) ? in[i] : 0;
#pragma unroll
    for (int d = 1; d < 64; d <<= 1) v += __shfl_xor(v, d, 64);
    int lane = tid & 63, w = tid >> 6;
    if (lane == 0) red[w] = v;
    __syncthreads();
    if (tid == 0) {
        int s = 0;
#pragma unroll
        for (int k = 0; k < 16; ++k) s += red[k];
        part[blockIdx.x] = s;
    }
}

__global__ void scan_mid_kernel(int* __restrict__ part, int nb,
                                int* __restrict__ total_out, int total_idx) {
    int lane = threadIdx.x;
    int orig = (lane < nb) ? part[lane] : 0;
    int v = orig;
#pragma unroll
    for (int d = 1; d < 64; d <<= 1) {
        int t = __shfl_up(v, d, 64);
        if (lane >= d) v += t;
    }
    if (lane < nb) part[lane] = v - orig;
    if (lane == 63) total_out[total_idx] = v;
}

__global__ __launch_bounds__(1024) void scan_final_kernel(const int* __restrict__ in,
                                                          const int* __restrict__ part,
                                                          int* __restrict__ rowptr,
                                                          int* __restrict__ cursor, int n) {
    __shared__ int woff[16];
    int tid = threadIdx.x;
    int i = blockIdx.x * 1024 + tid;
    int v = (i < n) ? in[i] : 0;
    int lane = tid & 63, w = tid >> 6;
    int x = v;
#pragma unroll
    for (int d = 1; d < 64; d <<= 1) {
        int t = __shfl_up(x, d, 64);
        if (lane >= d) x += t;
    }
    if (lane == 63) woff[w] = x;
    __syncthreads();
    if (tid == 0) {
        int s = 0;
#pragma unroll
        for (int k = 0; k < 16; ++k) { int t = woff[k]; woff[k] = s; s += t; }
    }
    __syncthreads();
    int excl = part[blockIdx.x] + woff[w] + x - v;
    if (i < n) { rowptr[i] = excl; cursor[i] = excl; }
}

// ---------------- convert: pool0 + f2b(+pad row) + wconv, block-range partitioned -----
// blocks [0,256): graph-pool of fp32 x (exact) ; [256,2304): x->bf16 ; [2304,2368): W->Wt

#define CVT_F2B_BLOCKS 2048
#define CVT_W_BLOCKS   64

__global__ __launch_bounds__(256) void convert_kernel(
    const float* __restrict__ x, unsigned short* __restrict__ xb,
    const float* __restrict__ W1, const float* __restrict__ W2,
    unsigned short* __restrict__ Wt1, unsigned short* __restrict__ Wt2,
    const int* __restrict__ gptr, float* __restrict__ pool0)
{
    __shared__ float red[DIM];
    int b = blockIdx.x, tid = threadIdx.x;
    if (b < N_GRAPHS) {
        int c = tid & 127;
        int half = tid >> 7;
        int beg = gptr[b], end = gptr[b + 1];
        float acc = 0.f;
        for (int n = beg + half; n < end; n += 2) acc += x[(size_t)n * DIM + c];
        if (half == 1) red[c] = acc;
        __syncthreads();
        if (half == 0) pool0[(size_t)b * DIM + c] = acc + red[c];
    } else if (b < N_GRAPHS + CVT_F2B_BLOCKS) {
        const int total_data = N_NODES * DIM / 4;
        const int total = (N_NODES + 1) * DIM / 4;   // includes zero fallback row
        const int stride = CVT_F2B_BLOCKS * 256;
        for (int i = (b - N_GRAPHS) * 256 + tid; i < total; i += stride) {
            uint2 o = make_uint2(0u, 0u);
            if (i < total_data) {
                float4 v = ((const float4*)x)[i];
                o = make_uint2(pack16(v.x, v.y), pack16(v.z, v.w));
            }
            ((uint2*)xb)[i] = o;
        }
    } else {
        const int total = (N_LAYERS - 1) * DIM * DIM;   // per weight tensor
        const int stride = CVT_W_BLOCKS * 256;
        for (int t = (b - N_GRAPHS - CVT_F2B_BLOCKS) * 256 + tid; t < total; t += stride) {
            int m = t >> 14;
            int k = (t & 16383) >> 7;
            int c = t & 127;
            size_t dstp = ((size_t)m << 14) + (size_t)c * DIM + k;
            Wt1[dstp] = f2bf(W1[t]);
            Wt2[dstp] = f2bf(W2[t]);
        }
    }
}

// ---------------- 8-wave GEMM core: 64x128 LDS A-tile, B-frags from L2 ----------------
// Wave wid: m-quarter mq=wid&3 (rows mq*16..+15), col-half ch=wid>>2 (cols ch*64..+63).
// mfma_f32_16x16x32_bf16 layouts verified rounds 3-9 (asymmetric weights passed).

__device__ __forceinline__ void gemm_core8(
    unsigned short (*As)[LDSP], const unsigned short* __restrict__ Wt,
    unsigned short* __restrict__ Z, float* __restrict__ colsum, float* __restrict__ colsumsq,
    int nrows, int row0, int tid)
{
    int wid = tid >> 6, lane = tid & 63;
    int mq = wid & 3, ch = wid >> 2;
    int m0 = mq * 16;
    int lrow = lane & 15;
    int lk = (lane >> 4) * 8;

    f32x4 acc[4];
#pragma unroll
    for (int n = 0; n < 4; ++n) acc[n] = (f32x4){0.f, 0.f, 0.f, 0.f};

#pragma unroll
    for (int kk = 0; kk < 4; ++kk) {
        int k0 = kk * 32;
        bf16x8 a = *(const bf16x8*)&As[m0 + lrow][k0 + lk];
#pragma unroll
        for (int n = 0; n < 4; ++n) {
            bf16x8 b = *(const bf16x8*)(Wt + (size_t)(ch * 64 + n * 16 + lrow) * DIM + k0 + lk);
            acc[n] = __builtin_amdgcn_mfma_f32_16x16x32_bf16(a, b, acc[n], 0, 0, 0);
        }
    }

    // epilogue: bf16 Z store + fp32 column stats (pad rows contribute exact 0)
    int r0 = row0 + m0 + (lane >> 4) * 4;
    float sarr[4], qarr[4];
#pragma unroll
    for (int n = 0; n < 4; ++n) {
        int col = ch * 64 + n * 16 + lrow;
        float s = 0.f, q = 0.f;
#pragma unroll
        for (int j = 0; j < 4; ++j) {
            float v = acc[n][j];
            int row = r0 + j;
            if (row < nrows) Z[(size_t)row * DIM + col] = f2bf(v);
            s += v; q += v * v;
        }
        s += __shfl_xor(s, 16); q += __shfl_xor(q, 16);
        s += __shfl_xor(s, 32); q += __shfl_xor(q, 32);
        sarr[n] = s; qarr[n] = q;
    }

    __syncthreads();
    float* red = (float*)&As[0][0];    // [8 waves][256]: sum at +col, sumsq at +128+col
    if (lane < 16) {
#pragma unroll
        for (int n = 0; n < 4; ++n) {
            int col = ch * 64 + n * 16 + lrow;
            red[wid * 256 + col]       = sarr[n];
            red[wid * 256 + 128 + col] = qarr[n];
        }
    }
    __syncthreads();
    if (tid < 128) {
        int col = tid;
        int base = (col >> 6) * 4 * 256;   // waves {0..3} own cols 0-63, {4..7} own 64-127
        float ts = red[base + col] + red[base + 256 + col]
                 + red[base + 512 + col] + red[base + 768 + col];
        float tq = red[base + 128 + col] + red[base + 384 + col]
                 + red[base + 640 + col] + red[base + 896 + col];
        atomicAdd(&colsum[col], ts);
        atomicAdd(&colsumsq[col], tq);
    }
}

// ---------------- gemmA: 2-node-concurrent SpMM gather + GEMM1 + stats ----------------
// lane = [nsel(1b) | esub(1b) | chunk(4b)]: 2 nodes per wave-step, 2 edge slots per node,
// chunk picks 16B of the 256B row. Fixed 16-edge batch (8 idx + 8 row loads back-to-back,
// deficit slots -> zero fallback row at index N_NODES); tail loop only for deg>16.
// 32 rows in flight per wave; ~2 latency exposures per 2-node step (4 steps/wave).

__global__ __launch_bounds__(512) void gemmA_kernel(
    const unsigned short* __restrict__ h, const int* __restrict__ rowptr,
    const int* __restrict__ csr, const float* __restrict__ epsArr, int l,
    const unsigned short* __restrict__ Wt, unsigned short* __restrict__ Z,
    float* __restrict__ stats, int nrows)
{
    __shared__ __attribute__((aligned(16))) unsigned short As[GEMM_BM][LDSP];
    int tid = threadIdx.x;
    int row0 = blockIdx.x * GEMM_BM;
    int wid = tid >> 6, lane = tid & 63;
    int nsel = lane >> 5, esub = (lane >> 4) & 1, chunk = lane & 15;
    float ep = 1.0f + epsArr[l];

    for (int t = 0; t < 4; ++t) {
        int node = row0 + wid * 8 + t * 2 + nsel;
        bool valid = node < nrows;
        int beg = 0, end = 0;
        if (valid) { beg = rowptr[node]; end = rowptr[node + 1]; }

        // fixed batch: edges beg .. beg+15 (2 subs x 8 slots), deficit -> zero row
        int sidx[8];
#pragma unroll
        for (int k = 0; k < 8; ++k) {
            int ee = beg + esub + 2 * k;
            int ec = (ee < N_EDGES) ? ee : (N_EDGES - 1);
            int sv = csr[ec];
            sidx[k] = (valid && ee < end) ? sv : N_NODES;
        }
        bf16x8 v[8];
#pragma unroll
        for (int k = 0; k < 8; ++k)
            v[k] = *(const bf16x8*)(h + (size_t)sidx[k] * DIM + chunk * 8);

        float a8[8];
#pragma unroll
        for (int j = 0; j < 8; ++j) a8[j] = 0.f;
#pragma unroll
        for (int k = 0; k < 8; ++k)
#pragma unroll
            for (int j = 0; j < 8; ++j)
                a8[j] += bf2f((unsigned short)v[k][j]);

        // tail: deg > 16 (2 edges/iter across the 2 subs)
        if (valid) {
            for (int e = beg + 16 + esub; e < end; e += 2) {
                int sv = csr[e];
                bf16x8 vv = *(const bf16x8*)(h + (size_t)sv * DIM + chunk * 8);
#pragma unroll
                for (int j = 0; j < 8; ++j) a8[j] += bf2f((unsigned short)vv[j]);
            }
        }

        // combine the 2 esub partials (lanes xor16 share node & chunk)
#pragma unroll
        for (int j = 0; j < 8; ++j) a8[j] += __shfl_xor(a8[j], 16);

        // self term
        if (valid) {
            bf16x8 hv = *(const bf16x8*)(h + (size_t)node * DIM + chunk * 8);
#pragma unroll
            for (int j = 0; j < 8; ++j) a8[j] += ep * bf2f((unsigned short)hv[j]);
        }

        if (esub == 0) {
            bf16x8 o;
#pragma unroll
            for (int j = 0; j < 8; ++j) o[j] = (short)f2bf(a8[j]);
            *(bf16x8*)&As[wid * 8 + t * 2 + nsel][chunk * 8] = o;
        }
    }
    __syncthreads();
    gemm_core8(As, Wt, Z, stats, stats + 128, nrows, row0, tid);
}

// ---------------- gemmB: fused BN1+ReLU staging + GEMM2 + stats ----------------

__global__ __launch_bounds__(512) void gemmB_kernel(
    const unsigned short* __restrict__ Zin, const float* __restrict__ statsIn,
    const float* __restrict__ g, const float* __restrict__ beta,
    const unsigned short* __restrict__ Wt, unsigned short* __restrict__ Zout,
    float* __restrict__ statsOut, int nrows)
{
    __shared__ __attribute__((aligned(16))) unsigned short As[GEMM_BM][LDSP];
    __shared__ float abn[DIM], shbn[DIM];
    int tid = threadIdx.x;
    int row0 = blockIdx.x * GEMM_BM;

    if (tid < DIM) {
        const float invN = 1.0f / (float)N_NODES;
        float m = statsIn[tid] * invN;
        float var = statsIn[128 + tid] * invN - m * m;
        float s = g[tid] * rsqrtf(var + BN_EPS);
        abn[tid] = s;
        shbn[tid] = beta[tid] - s * m;
    }
    __syncthreads();

#pragma unroll
    for (int it = 0; it < 2; ++it) {
        int c = tid + it * 512;
        int r = c >> 4, kc = c & 15;
        bf16x8 o = {0, 0, 0, 0, 0, 0, 0, 0};
        if (row0 + r < nrows) {     // pad rows stay exact 0
            bf16x8 v = *(const bf16x8*)(Zin + (size_t)(row0 + r) * DIM + kc * 8);
#pragma unroll
            for (int cc = 0; cc < 8; ++cc) {
                int col = kc * 8 + cc;
                float f = bf2f((unsigned short)v[cc]);
                f = fmaxf(fmaf(abn[col], f, shbn[col]), 0.f);
                o[cc] = (short)f2bf(f);
            }
        }
        *(bf16x8*)&As[r][kc * 8] = o;
    }
    __syncthreads();
    gemm_core8(As, Wt, Zout, statsOut, statsOut + 128, nrows, row0, tid);
}

// ---------------- bnpool: BN2+ReLU apply + h write + fused graph sum-pool ----------------

__global__ __launch_bounds__(256) void bnpool_kernel(
    const unsigned short* __restrict__ Zin, const float* __restrict__ stats,
    const float* __restrict__ g, const float* __restrict__ beta,
    const int* __restrict__ gid, unsigned short* __restrict__ hout,
    float* __restrict__ pooled, int nrows)
{
    __shared__ float abn[DIM], shbn[DIM];
    int tid = threadIdx.x;
    if (tid < DIM) {
        const float invN = 1.0f / (float)N_NODES;
        float m = stats[tid] * invN;
        float var = stats[128 + tid] * invN - m * m;
        float s = g[tid] * rsqrtf(var + BN_EPS);
        abn[tid] = s;
        shbn[tid] = beta[tid] - s * m;
    }
    __syncthreads();

    int row0 = blockIdx.x * GEMM_BM;
    int lane = tid & 63, w = tid >> 6;
    int c0 = lane * 2;
    float a0 = abn[c0], a1 = abn[c0 + 1], s0 = shbn[c0], s1 = shbn[c0 + 1];
    const unsigned int* Z2 = (const unsigned int*)Zin;
    unsigned int* H2 = (unsigned int*)hout;

    float px = 0.f, py = 0.f;
    int gcur = -1;
    for (int i = 0; i < 16; ++i) {
        int r = row0 + w * 16 + i;
        if (r >= nrows) break;
        int gg = gid[r];
        if (gg != gcur) {
            if (gcur >= 0) {
                atomicAdd(&pooled[(size_t)gcur * DIM + c0], px);
                atomicAdd(&pooled[(size_t)gcur * DIM + c0 + 1], py);
            }
            gcur = gg; px = 0.f; py = 0.f;
        }
        unsigned int v = Z2[(size_t)r * 64 + lane];
        float f0 = fmaxf(fmaf(a0, lo16(v), s0), 0.f);
        float f1 = fmaxf(fmaf(a1, hi16(v), s1), 0.f);
        unsigned int o = pack16(f0, f1);
        H2[(size_t)r * 64 + lane] = o;
        px += lo16(o);
        py += hi16(o);
    }
    if (gcur >= 0) {
        atomicAdd(&pooled[(size_t)gcur * DIM + c0], px);
        atomicAdd(&pooled[(size_t)gcur * DIM + c0 + 1], py);
    }
}

// ---------------- final readout ----------------

__global__ __launch_bounds__(256) void final_kernel(
    const float* __restrict__ pooledH, const float* __restrict__ Wp,
    const float* __restrict__ bp, float* __restrict__ outp)
{
    int t = blockIdx.x * blockDim.x + threadIdx.x;
    if (t >= N_GRAPHS * N_CLASSES) return;
    int g = t >> 4, c = t & 15;
    float acc = 0.f;
    for (int l = 0; l < N_LAYERS; ++l) {
        const float* ph = pooledH + ((size_t)l * N_GRAPHS + g) * DIM;
        const float* w = Wp + (size_t)l * DIM * N_CLASSES + c;
        float a = 0.f;
        for (int k = 0; k < DIM; ++k) a = fmaf(ph[k], w[k * N_CLASSES], a);
        acc += a + bp[l * N_CLASSES + c];
    }
    outp[t] = acc;
}

// ---------------- host launcher ----------------

extern "C" void kernel_launch(void* const* d_in, const int* in_sizes, int n_in,
                              void* d_out, int out_size, void* d_ws, size_t ws_size,
                              hipStream_t stream) {
    const float* x     = (const float*)d_in[0];
    const float* eps   = (const float*)d_in[1];
    const float* W1    = (const float*)d_in[2];
    const float* g1    = (const float*)d_in[4];
    const float* beta1 = (const float*)d_in[5];
    const float* W2    = (const float*)d_in[6];
    const float* g2    = (const float*)d_in[8];
    const float* beta2 = (const float*)d_in[9];
    const float* Wp    = (const float*)d_in[10];
    const float* bp    = (const float*)d_in[11];
    const int*   esrc  = (const int*)d_in[12];
    const int*   edst  = (const int*)d_in[13];
    const int*   gid   = (const int*)d_in[14];
    float* outp = (float*)d_out;

    char* ws = (char*)d_ws;
    size_t off = 0;
    auto alloc = [&](size_t bytes) {
        char* p = ws + off;
        off = (off + bytes + 255) & ~(size_t)255;
        return p;
    };
    // h buffers have one extra all-zero row (index N_NODES) as the gather fallback
    unsigned short* xb  = (unsigned short*)alloc((size_t)(N_NODES + 1) * DIM * 2);
    unsigned short* B0  = (unsigned short*)alloc((size_t)(N_NODES + 1) * DIM * 2);  // h ping
    unsigned short* B1  = (unsigned short*)alloc((size_t)(N_NODES + 1) * DIM * 2);  // h pong
    unsigned short* ZB  = (unsigned short*)alloc((size_t)N_NODES * DIM * 2);  // Z1
    unsigned short* Z2B = (unsigned short*)alloc((size_t)N_NODES * DIM * 2);  // Z2
    unsigned short* Wt1 = (unsigned short*)alloc((size_t)(N_LAYERS - 1) * DIM * DIM * 2);
    unsigned short* Wt2 = (unsigned short*)alloc((size_t)(N_LAYERS - 1) * DIM * DIM * 2);
    int*   csr     = (int*)alloc((size_t)N_EDGES * 4);
    int*   deg     = (int*)alloc((N_NODES + 1) * 4);
    int*   rowptr  = (int*)alloc((N_NODES + 1) * 4);
    int*   cursor  = (int*)alloc((N_NODES + 1) * 4);
    int*   part    = (int*)alloc(64 * 4);
    int*   growptr = (int*)alloc(300 * 4);
    float* stats   = (float*)alloc(8 * 256 * 4);   // [2*(L-1)] x {colsum[128], colsumsq[128]}
    float* pooledH = (float*)alloc((size_t)N_LAYERS * N_GRAPHS * DIM * 4);

    hipMemsetAsync(deg, 0, N_NODES * 4, stream);
    hipMemsetAsync(stats, 0, 8 * 256 * 4, stream);
    hipMemsetAsync(pooledH, 0, (size_t)N_LAYERS * N_GRAPHS * DIM * 4, stream);

    const int nsb = (N_NODES + 1023) / 1024;   // 49 scan blocks
    degbound_kernel<<<(N_EDGES + 255) / 256, 256, 0, stream>>>(edst, deg, gid, growptr);
    scan_part_kernel<<<nsb, 1024, 0, stream>>>(deg, part, N_NODES);
    scan_mid_kernel<<<1, 64, 0, stream>>>(part, nsb, rowptr, N_NODES);
    scan_final_kernel<<<nsb, 1024, 0, stream>>>(deg, part, rowptr, cursor, N_NODES);
    fill_csr_kernel<<<(N_EDGES + 255) / 256, 256, 0, stream>>>(esrc, edst, cursor, csr, N_EDGES);
    zrow_kernel<<<1, 64, 0, stream>>>(B0, B1);

    convert_kernel<<<N_GRAPHS + CVT_F2B_BLOCKS + CVT_W_BLOCKS, 256, 0, stream>>>(
        x, xb, W1, W2, Wt1, Wt2, growptr, pooledH);

    const int ngrid = (N_NODES + GEMM_BM - 1) / GEMM_BM;   // 782
    const unsigned short* hb = xb;
    unsigned short* nb = B0;
    for (int l = 0; l < N_LAYERS - 1; ++l) {
        float* statsA = stats + (size_t)(2 * l) * 256;
        float* statsB = stats + (size_t)(2 * l + 1) * 256;
        gemmA_kernel<<<ngrid, 512, 0, stream>>>(
            hb, rowptr, csr, eps, l, Wt1 + (size_t)l * DIM * DIM, ZB, statsA, N_NODES);
        gemmB_kernel<<<ngrid, 512, 0, stream>>>(
            ZB, statsA, g1 + (size_t)l * DIM, beta1 + (size_t)l * DIM,
            Wt2 + (size_t)l * DIM * DIM, Z2B, statsB, N_NODES);
        bnpool_kernel<<<ngrid, 256, 0, stream>>>(
            Z2B, statsB, g2 + (size_t)l * DIM, beta2 + (size_t)l * DIM,
            gid, nb, pooledH + (size_t)(l + 1) * N_GRAPHS * DIM, N_NODES);

        hb = nb;
        nb = (nb == B0) ? B1 : B0;
    }

    final_kernel<<<(N_GRAPHS * N_CLASSES + 255) / 256, 256, 0, stream>>>(pooledH, Wp, bp, outp);
}

// Round 11
// 653.772 us; speedup vs baseline: 1.0720x; 1.0720x over previous
//
#include <hip/hip_runtime.h>

#define N_NODES  50000
#define N_EDGES  800000
#define DIM      128
#define N_GRAPHS 256
#define N_CLASSES 16
#define N_LAYERS 5
#define BN_EPS   1e-5f

#define GEMM_BM 64
#define LDSP 136   // padded LDS row stride (bf16 elems): 272B breaks power-of-2 banking
#define ECAP 2048  // staged edges per block (8KB); avg block has ~1024

typedef short bf16x8 __attribute__((ext_vector_type(8)));
typedef float f32x4  __attribute__((ext_vector_type(4)));

__device__ __forceinline__ float bf2f(unsigned short u) {
    unsigned int x = ((unsigned int)u) << 16;
    return __builtin_bit_cast(float, x);
}
__device__ __forceinline__ unsigned short f2bf(float f) {
    unsigned int x = __builtin_bit_cast(unsigned int, f);
    x += 0x7fffu + ((x >> 16) & 1u);   // RNE
    return (unsigned short)(x >> 16);
}
__device__ __forceinline__ float lo16(unsigned int v) { return bf2f((unsigned short)(v & 0xffffu)); }
__device__ __forceinline__ float hi16(unsigned int v) { return bf2f((unsigned short)(v >> 16)); }
__device__ __forceinline__ unsigned int pack16(float a, float b) {
    return (unsigned int)f2bf(a) | ((unsigned int)f2bf(b) << 16);
}

// ---------------- CSR build: deg histogram + graph boundaries (merged) ----------------

__global__ void degbound_kernel(const int* __restrict__ dst, int* __restrict__ deg,
                                const int* __restrict__ gid, int* __restrict__ gptr) {
    int i = blockIdx.x * blockDim.x + threadIdx.x;
    if (i < N_EDGES) atomicAdd(&deg[dst[i]], 1);
    if (i < N_NODES) {
        int cur = gid[i];
        int prev = (i == 0) ? -1 : gid[i - 1];
        for (int g = prev + 1; g <= cur; ++g) gptr[g] = i;
        if (i == N_NODES - 1)
            for (int g = cur + 1; g <= N_GRAPHS; ++g) gptr[g] = N_NODES;
    }
}

__global__ void fill_csr_kernel(const int* __restrict__ src, const int* __restrict__ dst,
                                int* __restrict__ cursor, int* __restrict__ csr, int e_count) {
    int e = blockIdx.x * blockDim.x + threadIdx.x;
    if (e < e_count) {
        int d = dst[e];
        int p = atomicAdd(&cursor[d], 1);
        csr[p] = src[e];
    }
}

// ---------------- fast 3-phase exclusive scan (rowptr over 50000 degrees) ----------------

__global__ __launch_bounds__(1024) void scan_part_kernel(const int* __restrict__ in,
                                                         int* __restrict__ part, int n) {
    __shared__ int red[16];
    int tid = threadIdx.x;
    int i = blockIdx.x * 1024 + tid;
    int v = (i < n) ? in[i] : 0;
#pragma unroll
    for (int d = 1; d < 64; d <<= 1) v += __shfl_xor(v, d, 64);
    int lane = tid & 63, w = tid >> 6;
    if (lane == 0) red[w] = v;
    __syncthreads();
    if (tid == 0) {
        int s = 0;
#pragma unroll
        for (int k = 0; k < 16; ++k) s += red[k];
        part[blockIdx.x] = s;
    }
}

__global__ void scan_mid_kernel(int* __restrict__ part, int nb,
                                int* __restrict__ total_out, int total_idx) {
    int lane = threadIdx.x;
    int orig = (lane < nb) ? part[lane] : 0;
    int v = orig;
#pragma unroll
    for (int d = 1; d < 64; d <<= 1) {
        int t = __shfl_up(v, d, 64);
        if (lane >= d) v += t;
    }
    if (lane < nb) part[lane] = v - orig;
    if (lane == 63) total_out[total_idx] = v;
}

__global__ __launch_bounds__(1024) void scan_final_kernel(const int* __restrict__ in,
                                                          const int* __restrict__ part,
                                                          int* __restrict__ rowptr,
                                                          int* __restrict__ cursor, int n) {
    __shared__ int woff[16];
    int tid = threadIdx.x;
    int i = blockIdx.x * 1024 + tid;
    int v = (i < n) ? in[i] : 0;
    int lane = tid & 63, w = tid >> 6;
    int x = v;
#pragma unroll
    for (int d = 1; d < 64; d <<= 1) {
        int t = __shfl_up(x, d, 64);
        if (lane >= d) x += t;
    }
    if (lane == 63) woff[w] = x;
    __syncthreads();
    if (tid == 0) {
        int s = 0;
#pragma unroll
        for (int k = 0; k < 16; ++k) { int t = woff[k]; woff[k] = s; s += t; }
    }
    __syncthreads();
    int excl = part[blockIdx.x] + woff[w] + x - v;
    if (i < n) { rowptr[i] = excl; cursor[i] = excl; }
}

// ---------------- convert: pool0 + f2b + wconv, block-range partitioned ----------------
// blocks [0,256): graph-pool of fp32 x (exact) ; [256,2304): x->bf16 ; [2304,2368): W->Wt

#define CVT_F2B_BLOCKS 2048
#define CVT_W_BLOCKS   64

__global__ __launch_bounds__(256) void convert_kernel(
    const float* __restrict__ x, unsigned short* __restrict__ xb,
    const float* __restrict__ W1, const float* __restrict__ W2,
    unsigned short* __restrict__ Wt1, unsigned short* __restrict__ Wt2,
    const int* __restrict__ gptr, float* __restrict__ pool0)
{
    __shared__ float red[DIM];
    int b = blockIdx.x, tid = threadIdx.x;
    if (b < N_GRAPHS) {
        int c = tid & 127;
        int half = tid >> 7;
        int beg = gptr[b], end = gptr[b + 1];
        float acc = 0.f;
        for (int n = beg + half; n < end; n += 2) acc += x[(size_t)n * DIM + c];
        if (half == 1) red[c] = acc;
        __syncthreads();
        if (half == 0) pool0[(size_t)b * DIM + c] = acc + red[c];
    } else if (b < N_GRAPHS + CVT_F2B_BLOCKS) {
        const int total = N_NODES * DIM / 4;
        const int stride = CVT_F2B_BLOCKS * 256;
        for (int i = (b - N_GRAPHS) * 256 + tid; i < total; i += stride) {
            float4 v = ((const float4*)x)[i];
            ((uint2*)xb)[i] = make_uint2(pack16(v.x, v.y), pack16(v.z, v.w));
        }
    } else {
        const int total = (N_LAYERS - 1) * DIM * DIM;   // per weight tensor
        const int stride = CVT_W_BLOCKS * 256;
        for (int t = (b - N_GRAPHS - CVT_F2B_BLOCKS) * 256 + tid; t < total; t += stride) {
            int m = t >> 14;
            int k = (t & 16383) >> 7;
            int c = t & 127;
            size_t dstp = ((size_t)m << 14) + (size_t)c * DIM + k;
            Wt1[dstp] = f2bf(W1[t]);
            Wt2[dstp] = f2bf(W2[t]);
        }
    }
}

// ---------------- 8-wave GEMM core: 64x128 LDS A-tile, B-frags from L2 ----------------
// Wave wid: m-quarter mq=wid&3 (rows mq*16..+15), col-half ch=wid>>2 (cols ch*64..+63).
// mfma_f32_16x16x32_bf16 layouts verified rounds 3-10 (asymmetric weights passed).

__device__ __forceinline__ void gemm_core8(
    unsigned short (*As)[LDSP], const unsigned short* __restrict__ Wt,
    unsigned short* __restrict__ Z, float* __restrict__ colsum, float* __restrict__ colsumsq,
    int nrows, int row0, int tid)
{
    int wid = tid >> 6, lane = tid & 63;
    int mq = wid & 3, ch = wid >> 2;
    int m0 = mq * 16;
    int lrow = lane & 15;
    int lk = (lane >> 4) * 8;

    f32x4 acc[4];
#pragma unroll
    for (int n = 0; n < 4; ++n) acc[n] = (f32x4){0.f, 0.f, 0.f, 0.f};

#pragma unroll
    for (int kk = 0; kk < 4; ++kk) {
        int k0 = kk * 32;
        bf16x8 a = *(const bf16x8*)&As[m0 + lrow][k0 + lk];
#pragma unroll
        for (int n = 0; n < 4; ++n) {
            bf16x8 b = *(const bf16x8*)(Wt + (size_t)(ch * 64 + n * 16 + lrow) * DIM + k0 + lk);
            acc[n] = __builtin_amdgcn_mfma_f32_16x16x32_bf16(a, b, acc[n], 0, 0, 0);
        }
    }

    // epilogue: bf16 Z store + fp32 column stats (pad rows contribute exact 0)
    int r0 = row0 + m0 + (lane >> 4) * 4;
    float sarr[4], qarr[4];
#pragma unroll
    for (int n = 0; n < 4; ++n) {
        int col = ch * 64 + n * 16 + lrow;
        float s = 0.f, q = 0.f;
#pragma unroll
        for (int j = 0; j < 4; ++j) {
            float v = acc[n][j];
            int row = r0 + j;
            if (row < nrows) Z[(size_t)row * DIM + col] = f2bf(v);
            s += v; q += v * v;
        }
        s += __shfl_xor(s, 16); q += __shfl_xor(q, 16);
        s += __shfl_xor(s, 32); q += __shfl_xor(q, 32);
        sarr[n] = s; qarr[n] = q;
    }

    __syncthreads();
    float* red = (float*)&As[0][0];    // [8 waves][256]: sum at +col, sumsq at +128+col
    if (lane < 16) {
#pragma unroll
        for (int n = 0; n < 4; ++n) {
            int col = ch * 64 + n * 16 + lrow;
            red[wid * 256 + col]       = sarr[n];
            red[wid * 256 + 128 + col] = qarr[n];
        }
    }
    __syncthreads();
    if (tid < 128) {
        int col = tid;
        int base = (col >> 6) * 4 * 256;   // waves {0..3} own cols 0-63, {4..7} own 64-127
        float ts = red[base + col] + red[base + 256 + col]
                 + red[base + 512 + col] + red[base + 768 + col];
        float tq = red[base + 128 + col] + red[base + 384 + col]
                 + red[base + 640 + col] + red[base + 896 + col];
        atomicAdd(&colsum[col], ts);
        atomicAdd(&colsumsq[col], tq);
    }
}

// ---------------- gemmA: LDS-staged-index SpMM gather (R6 tiers) + GEMM1 + stats ------
// Block's csr slice [rowptr[row0], rowptr[row0+64]) staged coalesced into LDS (avg ~1024
// edges); node loop = exact R6 adaptive 16/8/4/1 tiers but indices via ds_read — the
// csr-load -> row-load serial dependency leaves the critical path.
// sub = lane>>4 (edge slot), chunk = lane&15 (16B of the 256B row). 16 rows in flight.

// gather tiers over [beg,end) with index accessor IDX (LDS or global)
#define GATHER_TIERS(IDX)                                                        \
    {                                                                            \
        int e = beg;                                                             \
        for (; e + 16 <= end; e += 16) {                                         \
            int s0 = IDX(e + sub);                                               \
            int s1 = IDX(e + 4 + sub);                                           \
            int s2 = IDX(e + 8 + sub);                                           \
            int s3 = IDX(e + 12 + sub);                                          \
            bf16x8 v0 = *(const bf16x8*)(h + (size_t)s0 * DIM + chunk * 8);      \
            bf16x8 v1 = *(const bf16x8*)(h + (size_t)s1 * DIM + chunk * 8);      \
            bf16x8 v2 = *(const bf16x8*)(h + (size_t)s2 * DIM + chunk * 8);      \
            bf16x8 v3 = *(const bf16x8*)(h + (size_t)s3 * DIM + chunk * 8);      \
            _Pragma("unroll")                                                    \
            for (int j = 0; j < 8; ++j)                                          \
                a8[j] += (bf2f((unsigned short)v0[j]) + bf2f((unsigned short)v1[j])) \
                       + (bf2f((unsigned short)v2[j]) + bf2f((unsigned short)v3[j])); \
        }                                                                        \
        for (; e + 8 <= end; e += 8) {                                           \
            int s0 = IDX(e + sub);                                               \
            int s1 = IDX(e + 4 + sub);                                           \
            bf16x8 v0 = *(const bf16x8*)(h + (size_t)s0 * DIM + chunk * 8);      \
            bf16x8 v1 = *(const bf16x8*)(h + (size_t)s1 * DIM + chunk * 8);      \
            _Pragma("unroll")                                                    \
            for (int j = 0; j < 8; ++j)                                          \
                a8[j] += bf2f((unsigned short)v0[j]) + bf2f((unsigned short)v1[j]); \
        }                                                                        \
        for (; e + 4 <= end; e += 4) {                                           \
            int s0 = IDX(e + sub);                                               \
            bf16x8 v0 = *(const bf16x8*)(h + (size_t)s0 * DIM + chunk * 8);      \
            _Pragma("unroll")                                                    \
            for (int j = 0; j < 8; ++j) a8[j] += bf2f((unsigned short)v0[j]);    \
        }                                                                        \
        int rmn = end - e;                                                       \
        if (sub < rmn) {                                                         \
            int s0 = IDX(e + sub);                                               \
            bf16x8 v0 = *(const bf16x8*)(h + (size_t)s0 * DIM + chunk * 8);      \
            _Pragma("unroll")                                                    \
            for (int j = 0; j < 8; ++j) a8[j] += bf2f((unsigned short)v0[j]);    \
        }                                                                        \
    }

__global__ __launch_bounds__(512) void gemmA_kernel(
    const unsigned short* __restrict__ h, const int* __restrict__ rowptr,
    const int* __restrict__ csr, const float* __restrict__ epsArr, int l,
    const unsigned short* __restrict__ Wt, unsigned short* __restrict__ Z,
    float* __restrict__ stats, int nrows)
{
    __shared__ __attribute__((aligned(16))) unsigned short As[GEMM_BM][LDSP];
    __shared__ int Es[ECAP];
    __shared__ int Rp[GEMM_BM + 1];
    int tid = threadIdx.x;
    int row0 = blockIdx.x * GEMM_BM;
    int wid = tid >> 6, lane = tid & 63;
    int sub = lane >> 4, chunk = lane & 15;
    float ep = 1.0f + epsArr[l];

    // stage rowptr slice (block-local offsets) + csr slice
    int top = row0 + GEMM_BM; if (top > nrows) top = nrows;
    int e_base = rowptr[row0];
    int e_top  = rowptr[top];
    int ecount = e_top - e_base;
    if (tid <= GEMM_BM) {
        int nidx = row0 + tid;
        Rp[tid] = rowptr[nidx <= nrows ? nidx : nrows] - e_base;
    }
    int ecap = ecount < ECAP ? ecount : ECAP;
    for (int i = tid; i < ecap; i += 512) Es[i] = csr[e_base + i];
    __syncthreads();

    const int* csr_g = csr + e_base;   // global fallback (block-local indexing)

    for (int i = 0; i < 8; ++i) {
        int li = wid * 8 + i;
        int node = row0 + li;
        float a8[8];
#pragma unroll
        for (int j = 0; j < 8; ++j) a8[j] = 0.f;
        if (node < nrows) {
            int beg = Rp[li], end = Rp[li + 1];
            if (end <= ECAP) {
#define IDX_L(E) Es[E]
                GATHER_TIERS(IDX_L)
#undef IDX_L
            } else {
#define IDX_G(E) csr_g[E]
                GATHER_TIERS(IDX_G)
#undef IDX_G
            }
            // combine the 4 sub-group partials (all lanes end with the total)
#pragma unroll
            for (int j = 0; j < 8; ++j) {
                a8[j] += __shfl_xor(a8[j], 16);
                a8[j] += __shfl_xor(a8[j], 32);
            }
            // self term
            bf16x8 hv = *(const bf16x8*)(h + (size_t)node * DIM + chunk * 8);
#pragma unroll
            for (int j = 0; j < 8; ++j) a8[j] += ep * bf2f((unsigned short)hv[j]);
        }
        if (sub == 0) {
            bf16x8 o;
#pragma unroll
            for (int j = 0; j < 8; ++j) o[j] = (short)f2bf(a8[j]);
            *(bf16x8*)&As[wid * 8 + i][chunk * 8] = o;
        }
    }
    __syncthreads();
    gemm_core8(As, Wt, Z, stats, stats + 128, nrows, row0, tid);
}

// ---------------- gemmB: fused BN1+ReLU staging + GEMM2 + stats ----------------

__global__ __launch_bounds__(512) void gemmB_kernel(
    const unsigned short* __restrict__ Zin, const float* __restrict__ statsIn,
    const float* __restrict__ g, const float* __restrict__ beta,
    const unsigned short* __restrict__ Wt, unsigned short* __restrict__ Zout,
    float* __restrict__ statsOut, int nrows)
{
    __shared__ __attribute__((aligned(16))) unsigned short As[GEMM_BM][LDSP];
    __shared__ float abn[DIM], shbn[DIM];
    int tid = threadIdx.x;
    int row0 = blockIdx.x * GEMM_BM;

    if (tid < DIM) {
        const float invN = 1.0f / (float)N_NODES;
        float m = statsIn[tid] * invN;
        float var = statsIn[128 + tid] * invN - m * m;
        float s = g[tid] * rsqrtf(var + BN_EPS);
        abn[tid] = s;
        shbn[tid] = beta[tid] - s * m;
    }
    __syncthreads();

#pragma unroll
    for (int it = 0; it < 2; ++it) {
        int c = tid + it * 512;
        int r = c >> 4, kc = c & 15;
        bf16x8 o = {0, 0, 0, 0, 0, 0, 0, 0};
        if (row0 + r < nrows) {     // pad rows stay exact 0
            bf16x8 v = *(const bf16x8*)(Zin + (size_t)(row0 + r) * DIM + kc * 8);
#pragma unroll
            for (int cc = 0; cc < 8; ++cc) {
                int col = kc * 8 + cc;
                float f = bf2f((unsigned short)v[cc]);
                f = fmaxf(fmaf(abn[col], f, shbn[col]), 0.f);
                o[cc] = (short)f2bf(f);
            }
        }
        *(bf16x8*)&As[r][kc * 8] = o;
    }
    __syncthreads();
    gemm_core8(As, Wt, Zout, statsOut, statsOut + 128, nrows, row0, tid);
}

// ---------------- bnpool: BN2+ReLU apply + h write + fused graph sum-pool ----------------

__global__ __launch_bounds__(256) void bnpool_kernel(
    const unsigned short* __restrict__ Zin, const float* __restrict__ stats,
    const float* __restrict__ g, const float* __restrict__ beta,
    const int* __restrict__ gid, unsigned short* __restrict__ hout,
    float* __restrict__ pooled, int nrows)
{
    __shared__ float abn[DIM], shbn[DIM];
    int tid = threadIdx.x;
    if (tid < DIM) {
        const float invN = 1.0f / (float)N_NODES;
        float m = stats[tid] * invN;
        float var = stats[128 + tid] * invN - m * m;
        float s = g[tid] * rsqrtf(var + BN_EPS);
        abn[tid] = s;
        shbn[tid] = beta[tid] - s * m;
    }
    __syncthreads();

    int row0 = blockIdx.x * GEMM_BM;
    int lane = tid & 63, w = tid >> 6;
    int c0 = lane * 2;
    float a0 = abn[c0], a1 = abn[c0 + 1], s0 = shbn[c0], s1 = shbn[c0 + 1];
    const unsigned int* Z2 = (const unsigned int*)Zin;
    unsigned int* H2 = (unsigned int*)hout;

    float px = 0.f, py = 0.f;
    int gcur = -1;
    for (int i = 0; i < 16; ++i) {
        int r = row0 + w * 16 + i;
        if (r >= nrows) break;
        int gg = gid[r];
        if (gg != gcur) {
            if (gcur >= 0) {
                atomicAdd(&pooled[(size_t)gcur * DIM + c0], px);
                atomicAdd(&pooled[(size_t)gcur * DIM + c0 + 1], py);
            }
            gcur = gg; px = 0.f; py = 0.f;
        }
        unsigned int v = Z2[(size_t)r * 64 + lane];
        float f0 = fmaxf(fmaf(a0, lo16(v), s0), 0.f);
        float f1 = fmaxf(fmaf(a1, hi16(v), s1), 0.f);
        unsigned int o = pack16(f0, f1);
        H2[(size_t)r * 64 + lane] = o;
        px += lo16(o);
        py += hi16(o);
    }
    if (gcur >= 0) {
        atomicAdd(&pooled[(size_t)gcur * DIM + c0], px);
        atomicAdd(&pooled[(size_t)gcur * DIM + c0 + 1], py);
    }
}

// ---------------- final readout ----------------

__global__ __launch_bounds__(256) void final_kernel(
    const float* __restrict__ pooledH, const float* __restrict__ Wp,
    const float* __restrict__ bp, float* __restrict__ outp)
{
    int t = blockIdx.x * blockDim.x + threadIdx.x;
    if (t >= N_GRAPHS * N_CLASSES) return;
    int g = t >> 4, c = t & 15;
    float acc = 0.f;
    for (int l = 0; l < N_LAYERS; ++l) {
        const float* ph = pooledH + ((size_t)l * N_GRAPHS + g) * DIM;
        const float* w = Wp + (size_t)l * DIM * N_CLASSES + c;
        float a = 0.f;
        for (int k = 0; k < DIM; ++k) a = fmaf(ph[k], w[k * N_CLASSES], a);
        acc += a + bp[l * N_CLASSES + c];
    }
    outp[t] = acc;
}

// ---------------- host launcher ----------------

extern "C" void kernel_launch(void* const* d_in, const int* in_sizes, int n_in,
                              void* d_out, int out_size, void* d_ws, size_t ws_size,
                              hipStream_t stream) {
    const float* x     = (const float*)d_in[0];
    const float* eps   = (const float*)d_in[1];
    const float* W1    = (const float*)d_in[2];
    const float* g1    = (const float*)d_in[4];
    const float* beta1 = (const float*)d_in[5];
    const float* W2    = (const float*)d_in[6];
    const float* g2    = (const float*)d_in[8];
    const float* beta2 = (const float*)d_in[9];
    const float* Wp    = (const float*)d_in[10];
    const float* bp    = (const float*)d_in[11];
    const int*   esrc  = (const int*)d_in[12];
    const int*   edst  = (const int*)d_in[13];
    const int*   gid   = (const int*)d_in[14];
    float* outp = (float*)d_out;

    char* ws = (char*)d_ws;
    size_t off = 0;
    auto alloc = [&](size_t bytes) {
        char* p = ws + off;
        off = (off + bytes + 255) & ~(size_t)255;
        return p;
    };
    unsigned short* xb  = (unsigned short*)alloc((size_t)N_NODES * DIM * 2);
    unsigned short* B0  = (unsigned short*)alloc((size_t)N_NODES * DIM * 2);  // h ping
    unsigned short* B1  = (unsigned short*)alloc((size_t)N_NODES * DIM * 2);  // h pong
    unsigned short* ZB  = (unsigned short*)alloc((size_t)N_NODES * DIM * 2);  // Z1
    unsigned short* Z2B = (unsigned short*)alloc((size_t)N_NODES * DIM * 2);  // Z2
    unsigned short* Wt1 = (unsigned short*)alloc((size_t)(N_LAYERS - 1) * DIM * DIM * 2);
    unsigned short* Wt2 = (unsigned short*)alloc((size_t)(N_LAYERS - 1) * DIM * DIM * 2);
    int*   csr     = (int*)alloc((size_t)N_EDGES * 4);
    int*   deg     = (int*)alloc((N_NODES + 1) * 4);
    int*   rowptr  = (int*)alloc((N_NODES + 1) * 4);
    int*   cursor  = (int*)alloc((N_NODES + 1) * 4);
    int*   part    = (int*)alloc(64 * 4);
    int*   growptr = (int*)alloc(300 * 4);
    float* stats   = (float*)alloc(8 * 256 * 4);   // [2*(L-1)] x {colsum[128], colsumsq[128]}
    float* pooledH = (float*)alloc((size_t)N_LAYERS * N_GRAPHS * DIM * 4);

    hipMemsetAsync(deg, 0, N_NODES * 4, stream);
    hipMemsetAsync(stats, 0, 8 * 256 * 4, stream);
    hipMemsetAsync(pooledH, 0, (size_t)N_LAYERS * N_GRAPHS * DIM * 4, stream);

    const int nsb = (N_NODES + 1023) / 1024;   // 49 scan blocks
    degbound_kernel<<<(N_EDGES + 255) / 256, 256, 0, stream>>>(edst, deg, gid, growptr);
    scan_part_kernel<<<nsb, 1024, 0, stream>>>(deg, part, N_NODES);
    scan_mid_kernel<<<1, 64, 0, stream>>>(part, nsb, rowptr, N_NODES);
    scan_final_kernel<<<nsb, 1024, 0, stream>>>(deg, part, rowptr, cursor, N_NODES);
    fill_csr_kernel<<<(N_EDGES + 255) / 256, 256, 0, stream>>>(esrc, edst, cursor, csr, N_EDGES);

    convert_kernel<<<N_GRAPHS + CVT_F2B_BLOCKS + CVT_W_BLOCKS, 256, 0, stream>>>(
        x, xb, W1, W2, Wt1, Wt2, growptr, pooledH);

    const int ngrid = (N_NODES + GEMM_BM - 1) / GEMM_BM;   // 782
    const unsigned short* hb = xb;
    unsigned short* nb = B0;
    for (int l = 0; l < N_LAYERS - 1; ++l) {
        float* statsA = stats + (size_t)(2 * l) * 256;
        float* statsB = stats + (size_t)(2 * l + 1) * 256;
        gemmA_kernel<<<ngrid, 512, 0, stream>>>(
            hb, rowptr, csr, eps, l, Wt1 + (size_t)l * DIM * DIM, ZB, statsA, N_NODES);
        gemmB_kernel<<<ngrid, 512, 0, stream>>>(
            ZB, statsA, g1 + (size_t)l * DIM, beta1 + (size_t)l * DIM,
            Wt2 + (size_t)l * DIM * DIM, Z2B, statsB, N_NODES);
        bnpool_kernel<<<ngrid, 256, 0, stream>>>(
            Z2B, statsB, g2 + (size_t)l * DIM, beta2 + (size_t)l * DIM,
            gid, nb, pooledH + (size_t)(l + 1) * N_GRAPHS * DIM, N_NODES);

        hb = nb;
        nb = (nb == B0) ? B1 : B0;
    }

    final_kernel<<<(N_GRAPHS * N_CLASSES + 255) / 256, 256, 0, stream>>>(pooledH, Wp, bp, outp);
}